// Round 14
// baseline (81.919 us; speedup 1.0000x reference)
//
#include <hip/hip_runtime.h>

// NEUROPULS unitary mesh, N=256 — R17: G=2 stage-split + zero-LDS combine.
// R16 post-mortem: packed core gained 2us; calibrated model (eff. clock
// ~1.4-1.6 GHz from VALUBusy across R6/R10) says per-stage wall ~310cy with
// ~70cy issue — instruction levers are cy-for-cy now. Remaining 2x lever:
// chain LENGTH. R13/R14 proved the associativity split numerically; R14's
// cgemm lost because it was LDS-throughput-bound (2:1 FMA:read). This
// combine has NO LDS: P1/P2 stored row-major float2; block computes 2
// output rows; A-row entries are wave-uniform (scalar loads), B-rows
// stream coalesced (2KB/k per block); 8 FMA per 8B-load per thread.
//   P1 = S64..S1*D0 (g=0), P2 = D129*S128..S65 (g=1), M = P2 x P1.
// Group phase: 512 blocks (2/CU, separate SIMDs), 64-stage chains using
// R16's verified packed core + 8-chunk DMA machinery.
// ws (floats): coefs[98304] | P1 @98304 (float2 row-major [r*256+c]) |
//              P2 @229376.

__device__ __forceinline__ float dpp_up1(float x) {   // wave_shr:1, n <- n-1
    return __int_as_float(__builtin_amdgcn_update_dpp(
        __float_as_int(x), __float_as_int(x), 0x138, 0xf, 0xf, false));
}
__device__ __forceinline__ float dpp_dn1(float x) {   // wave_shl:1, n <- n+1
    return __int_as_float(__builtin_amdgcn_update_dpp(
        __float_as_int(x), __float_as_int(x), 0x130, 0xf, 0xf, false));
}
__device__ __forceinline__ void sincos4(float4 th, float sn[4], float cs[4]) {
    __sincosf(th.x, &sn[0], &cs[0]);
    __sincosf(th.y, &sn[1], &cs[1]);
    __sincosf(th.z, &sn[2], &cs[2]);
    __sincosf(th.w, &sn[3], &cs[3]);
}

// packed complex helpers (verified R16)
__device__ __forceinline__ float2 cmul_pk(float2 K, float2 z) {
    float2 t;
    asm("v_pk_mul_f32 %0, %1, %2 op_sel:[0,0] op_sel_hi:[0,1]\n\t"
        "v_pk_fma_f32 %0, %1, %2, %0 op_sel:[1,1,0] op_sel_hi:[1,0,1] neg_lo:[1,0,0]"
        : "=&v"(t) : "v"(K), "v"(z));
    return t;
}
__device__ __forceinline__ float2 cfma_pk(float2 K, float2 z, float2 acc) {
    asm("v_pk_fma_f32 %0, %1, %2, %0 op_sel:[0,0,0] op_sel_hi:[0,1,1]\n\t"
        "v_pk_fma_f32 %0, %1, %2, %0 op_sel:[1,1,0] op_sel_hi:[1,0,1] neg_lo:[1,0,0]"
        : "+v"(acc) : "v"(K), "v"(z));
    return acc;
}
__device__ __forceinline__ float2 cross_pk(float2 K, float2 z, float2 p) {
    float2 t;
    asm("v_pk_mul_f32 %0, %1, %2 op_sel:[0,0] op_sel_hi:[0,1]\n\t"
        "v_pk_fma_f32 %0, %1, %3, %0 op_sel:[1,1,0] op_sel_hi:[1,0,1] neg_lo:[1,0,0]"
        : "=&v"(t) : "v"(K), "v"(z), "v"(p));
    return t;
}

// ---------- kernel 1: per-stage collapsed coefficients (verified) ----------
__global__ __launch_bounds__(64)
void coef_kernel(const float* __restrict__ thetas,  // [130,256]
                 float* __restrict__ coefs)         // 128*3*64 float4
{
    const int s0   = blockIdx.x;    // 0..127 -> theta row s0+1
    const int lane = threadIdx.x;   // 0..63

    const float U  = 0.98f * 0.505f;                  // AT^2
    const float W  = 0.98f * 0.495f;                  // AR^2
    const float Gc = 0.98f * sqrtf(0.505f * 0.495f);  // AT*AR

    float4 th = *(const float4*)(thetas + (s0 + 1) * 256 + 4 * lane);
    float s[4], c[4];
    sincos4(th, s, c);

    float4 A, B, C;
    A.x = U * c[0] - W * c[1];   A.y = U * s[0] - W * s[1];   // E0
    A.z = U * c[1] - W * c[0];   A.w = U * s[1] - W * s[0];   // F0
    B.x = -Gc * (s[0] + s[1]);   B.y = Gc * (c[0] + c[1]);    // G0
    B.z = -Gc * (s[2] + s[3]);   B.w = Gc * (c[2] + c[3]);    // G1
    C.x = U * c[2] - W * c[3];   C.y = U * s[2] - W * s[3];   // E1
    C.z = U * c[3] - W * c[2];   C.w = U * s[3] - W * s[2];   // F1

    float4* cp = (float4*)coefs;
    cp[(s0 * 3 + 0) * 64 + lane] = A;
    cp[(s0 * 3 + 1) * 64 + lane] = B;
    cp[(s0 * 3 + 2) * 64 + lane] = C;
}

// ---------- kernel 2: half-operator propagation (64 stages, packed) -------
__global__ __launch_bounds__(64, 1)
void group_kernel(const float* __restrict__ thetas,  // [130,256]
                  const float* __restrict__ coefs,   // from k1
                  float* __restrict__ ws)
{
    constexpr int N = 256;
    __shared__ float4 cbuf[2][1536];   // 2 x 24 KB (8-stage chunks)

    const int g    = blockIdx.x >> 8;    // 0: stages 1..64; 1: 65..128
    const int col  = blockIdx.x & 255;
    const int lane = threadIdx.x;
    const int base = g * 8;              // global chunk offset (0 or 8)

    const float BT = sqrtf(0.98f * 0.01f);
    const float BR = sqrtf(0.98f * 0.99f);
    const float2 CK  = make_float2(BT, BR);
    const float2 EC0 = (lane == 0)  ? make_float2(BR, 0.f) : CK;  // row 0 thru
    const float2 EC3 = (lane == 63) ? make_float2(BR, 0.f) : CK;  // row 255 thru

    // state: rows 4*lane..4*lane+3 of column col, packed [re,im]
    float2 z0 = make_float2(0.f, 0.f), z1 = z0, z2 = z0, z3 = z0;

    // init: g=0 -> diag(exp(i*theta0)) column; g=1 -> identity column
    {
        const int r0 = col - 4 * lane;
        if (0 <= r0 && r0 < 4) {
            float2 v = make_float2(1.f, 0.f);
            if (g == 0) {
                float s0, c0;
                __sincosf(thetas[col], &s0, &c0);
                v = make_float2(c0, s0);
            }
            if (r0 == 0) z0 = v; else if (r0 == 1) z1 = v;
            else if (r0 == 2) z2 = v; else z3 = v;
        }
    }

    auto mstep = [&](const float4& KA, const float4& KB, const float4& KC) {
        const float2 E0 = make_float2(KA.x, KA.y), F0 = make_float2(KA.z, KA.w);
        const float2 G0 = make_float2(KB.x, KB.y), G1 = make_float2(KB.z, KB.w);
        const float2 E1 = make_float2(KC.x, KC.y), F1 = make_float2(KC.z, KC.w);
        const float2 nx0 = cfma_pk(G0, z1, cmul_pk(E0, z0));
        const float2 ny0 = cfma_pk(F0, z1, cmul_pk(G0, z0));
        const float2 nx1 = cfma_pk(G1, z3, cmul_pk(E1, z2));
        const float2 ny1 = cfma_pk(F1, z3, cmul_pk(G1, z2));
        z0 = nx0; z1 = ny0; z2 = nx1; z3 = ny1;
    };
    auto crossing = [&]() {
        const float2 pv3 = make_float2(dpp_up1(z3.x), dpp_up1(z3.y));
        const float2 nv0 = make_float2(dpp_dn1(z0.x), dpp_dn1(z0.y));
        const float2 t1 = cross_pk(CK, z1, z2);
        const float2 t2 = cross_pk(CK, z2, z1);
        z0 = cross_pk(EC0, z0, pv3);
        z3 = cross_pk(EC3, z3, nv0);
        z1 = t1; z2 = t2;
    };

    auto issue_chunk = [&](int c) {    // c = local chunk 0..7
        const float4* src = (const float4*)coefs + ((base + c) * 24) * 64 + lane;
        float4* dst = &cbuf[c & 1][0];
        #pragma unroll
        for (int j = 0; j < 24; ++j)
            __builtin_amdgcn_global_load_lds(
                (const __attribute__((address_space(1))) void*)(src + j * 64),
                (__attribute__((address_space(3))) void*)(dst + j * 64),
                16, 0, 0);
    };

    issue_chunk(0);
    issue_chunk(1);
    asm volatile("s_waitcnt vmcnt(24)" ::: "memory");
    __builtin_amdgcn_sched_barrier(0);

    // local chunks 0..6 (8 full stages each; all have crossing: s <= 120)
    for (int c = 0; c < 7; ++c) {
        const int cb = c & 1;
        float4 KA[8], KB[8], KC[8];
        #pragma unroll
        for (int k = 0; k < 8; ++k) {
            const float4* p = &cbuf[cb][k * 192 + lane];
            KA[k] = p[0]; KB[k] = p[64]; KC[k] = p[128];
        }
        asm volatile("s_waitcnt lgkmcnt(0)" ::: "memory");
        __builtin_amdgcn_sched_barrier(0);
        if (c <= 5) issue_chunk(c + 2);
        #pragma unroll
        for (int k = 0; k < 8; ++k) {
            mstep(KA[k], KB[k], KC[k]);
            crossing();
        }
        if (c <= 5)
            asm volatile("s_waitcnt vmcnt(24)" ::: "memory");
        else
            asm volatile("s_waitcnt vmcnt(0)" ::: "memory");   // chunk 7 landed
        __builtin_amdgcn_sched_barrier(0);
    }

    // local chunk 7 (buffer 1): g=0 -> stages 57..64 all crossing;
    //                           g=1 -> stages 121..128, s=128 mstep-only
    {
        float4 KA[8], KB[8], KC[8];
        #pragma unroll
        for (int k = 0; k < 8; ++k) {
            const float4* p = &cbuf[1][k * 192 + lane];
            KA[k] = p[0]; KB[k] = p[64]; KC[k] = p[128];
        }
        asm volatile("s_waitcnt lgkmcnt(0)" ::: "memory");
        __builtin_amdgcn_sched_barrier(0);
        #pragma unroll
        for (int k = 0; k < 7; ++k) {
            mstep(KA[k], KB[k], KC[k]);
            crossing();
        }
        mstep(KA[7], KB[7], KC[7]);
        if (g == 0) crossing();            // s=64 has crossing; s=128 not
    }

    // g=1: fold D129 row phases (rows 4*lane..+3)
    if (g == 1) {
        float4 thF = *(const float4*)(thetas + 129 * N + 4 * lane);
        float sn[4], cs[4];
        sincos4(thF, sn, cs);
        z0 = cmul_pk(make_float2(cs[0], sn[0]), z0);
        z1 = cmul_pk(make_float2(cs[1], sn[1]), z1);
        z2 = cmul_pk(make_float2(cs[2], sn[2]), z2);
        z3 = cmul_pk(make_float2(cs[3], sn[3]), z3);
    }

    // store column col of P_g ROW-MAJOR float2: P[r*256+col]
    {
        float2* pb = (float2*)(ws + (g == 0 ? 98304 : 229376));
        const int r = 4 * lane;
        pb[(r + 0) * 256 + col] = z0;
        pb[(r + 1) * 256 + col] = z1;
        pb[(r + 2) * 256 + col] = z2;
        pb[(r + 3) * 256 + col] = z3;
    }
}

// ---------- kernel 3: M = P2 x P1, zero-LDS combine ----------
__global__ __launch_bounds__(256)
void combine_kernel(const float* __restrict__ ws,
                    float* __restrict__ out)       // re[65536] || im[65536]
{
    const int c  = threadIdx.x;          // column 0..255
    const int r0 = blockIdx.x * 2;       // rows r0, r0+1

    const float2* A = (const float2*)(ws + 229376);  // P2 row-major
    const float2* B = (const float2*)(ws + 98304);   // P1 row-major
    const float2* a0p = A + (size_t)r0 * 256;        // wave-uniform stream
    const float2* a1p = A + (size_t)(r0 + 1) * 256;
    const float2* bp  = B + c;                       // coalesced stream

    float ar0 = 0.f, ai0 = 0.f, ar1 = 0.f, ai1 = 0.f;
    #pragma unroll 8
    for (int k = 0; k < 256; ++k) {
        const float2 a0 = a0p[k];
        const float2 a1 = a1p[k];
        const float2 b  = bp[(size_t)k * 256];
        ar0 += a0.x * b.x - a0.y * b.y;
        ai0 += a0.x * b.y + a0.y * b.x;
        ar1 += a1.x * b.x - a1.y * b.y;
        ai1 += a1.x * b.y + a1.y * b.x;
    }

    const int i0 = r0 * 256 + c;
    out[i0]               = ar0;
    out[65536 + i0]       = ai0;
    out[i0 + 256]         = ar1;
    out[65536 + i0 + 256] = ai1;
}

extern "C" void kernel_launch(void* const* d_in, const int* in_sizes, int n_in,
                              void* d_out, int out_size, void* d_ws, size_t ws_size,
                              hipStream_t stream)
{
    const float* thetas = (const float*)d_in[0];   // [130,256] fp32
    float* out = (float*)d_out;                    // planar: re[65536] || im[65536]
    float* ws  = (float*)d_ws;
    (void)in_sizes; (void)n_in; (void)out_size; (void)ws_size;

    coef_kernel   <<<dim3(128), dim3(64),  0, stream>>>(thetas, ws);
    group_kernel  <<<dim3(512), dim3(64),  0, stream>>>(thetas, ws, ws);
    combine_kernel<<<dim3(128), dim3(256), 0, stream>>>(ws, out);
}